// Round 11
// baseline (309.873 us; speedup 1.0000x reference)
//
#include <hip/hip_runtime.h>
#include <hip/hip_bf16.h>

// Problem shapes (fixed by setup_inputs)
#define B_    1024
#define D_    768
#define POOL_ 100
#define KPAD  128                        // pool padded for transposed layout
#define PLEN_ 8
#define TOPK_ 3
#define EK_ELEMS (B_ * 4 * D_)           // 3,145,728
#define XB_ELEMS (B_ * 197 * D_)         // 154,976,256
#define XB_F4    (XB_ELEMS / 4)          // 38,744,064 float4s

#define BT 8                             // b-rows per score block (R10: 4)
#define SCORE_BLOCKS (B_ / BT)           // 128
#define COPY_BLOCKS  8192                // R7-proven 6.4 TB/s config
#define NBLOCKS (SCORE_BLOCKS + COPY_BLOCKS)

typedef float  f4_t __attribute__((ext_vector_type(4)));
typedef double d2_t __attribute__((ext_vector_type(2)));

// ---------------------------------------------------------------------------
// Kernel 1: prep. For k<100: sm = softmax(A[k,:]), n = ||K[k,:]||, write
//   W_T[d][k] = { sm_d * K[k,d]/n,  sm_d * sm_d }   (double2, k-contiguous)
// For k in [100,128): zero pad columns (pad scores = 0 but are excluded from
// top-3 anyway since only k<100 participates).
// ---------------------------------------------------------------------------
__global__ void prep_kernel(const float* __restrict__ A, const float* __restrict__ K,
                            d2_t* __restrict__ W_T) {
    const int k = blockIdx.x;
    const int t = threadIdx.x;

    if (k >= POOL_) {
        for (int d = t; d < D_; d += 256)
            W_T[(size_t)d * KPAD + k] = d2_t{0.0, 0.0};
        return;
    }

    const int wave = t >> 6, lane = t & 63;
    __shared__ double red[4];

    double m = -1e300;
    for (int d = t; d < D_; d += 256) m = fmax(m, (double)A[k * D_ + d]);
    #pragma unroll
    for (int off = 32; off >= 1; off >>= 1) m = fmax(m, __shfl_xor(m, off));
    if (lane == 0) red[wave] = m;
    __syncthreads();
    m = fmax(fmax(red[0], red[1]), fmax(red[2], red[3]));
    __syncthreads();

    double s = 0.0;
    for (int d = t; d < D_; d += 256) s += exp((double)A[k * D_ + d] - m);
    #pragma unroll
    for (int off = 32; off >= 1; off >>= 1) s += __shfl_xor(s, off);
    if (lane == 0) red[wave] = s;
    __syncthreads();
    s = red[0] + red[1] + red[2] + red[3];
    __syncthreads();

    double ss = 0.0;
    for (int d = t; d < D_; d += 256) {
        double v = (double)K[k * D_ + d];
        ss += v * v;
    }
    #pragma unroll
    for (int off = 32; off >= 1; off >>= 1) ss += __shfl_xor(ss, off);
    if (lane == 0) red[wave] = ss;
    __syncthreads();
    ss = red[0] + red[1] + red[2] + red[3];
    const double n = fmax(sqrt(ss), 1e-12);

    for (int d = t; d < D_; d += 256) {
        const double smd = exp((double)A[k * D_ + d] - m) / s;
        W_T[(size_t)d * KPAD + k] = d2_t{smd * ((double)K[k * D_ + d] / n),
                                         smd * smd};
    }
}

// ---------------------------------------------------------------------------
// Kernel 2 (fused score + copy, champion structure):
//  blocks [0,128):    score BT=8 rows. 256 thr = 128 klane x 2 dhalf; each
//                     thread accumulates all 8 rows -> per-block external
//                     W traffic 1.5 MB, total 192 MB (R10: 384 MB; L2
//                     pollution from the copy makes this ~= HBM traffic).
//                     One double2 load per iter (1 KB/wave), no shuffles.
//  blocks [128,8320): R7-proven plain grid-stride float4 copy (6.4 TB/s).
// ---------------------------------------------------------------------------
__global__ void __launch_bounds__(256)
fused_kernel(const float* __restrict__ xq,
             const d2_t* __restrict__ W_T,
             const float* __restrict__ p,
             const f4_t* __restrict__ xb,
             float* __restrict__ out) {
    const int t = threadIdx.x;

    if (blockIdx.x >= SCORE_BLOCKS) {
        // ---------------- copy role ----------------
        f4_t* __restrict__ dst = (f4_t*)(out + 2 * (size_t)EK_ELEMS);
        size_t i = (size_t)(blockIdx.x - SCORE_BLOCKS) * 256 + t;
        const size_t stride = (size_t)COPY_BLOCKS * 256;
        for (; i < (size_t)XB_F4; i += stride)
            dst[i] = xb[i];
        return;
    }

    // ---------------- score role ----------------
    __shared__ double s_hd[BT][KPAD];     // dhalf=1 partial dots (16 KB)
    __shared__ double s_hq[BT][KPAD];     // dhalf=1 partial sqs  (16 KB... f64)
    __shared__ double s_aq[BT][KPAD];     // final scores
    __shared__ int    s_idx[BT][TOPK_];

    const int b0    = blockIdx.x * BT;
    const int klane = t & (KPAD - 1);
    const int dhalf = t >> 7;             // wave-uniform (waves 0,1 / 2,3)
    const int dbeg  = dhalf * (D_ / 2);

    double dot[BT], sq[BT];
    #pragma unroll
    for (int bl = 0; bl < BT; ++bl) { dot[bl] = 0.0; sq[bl] = 0.0; }

    #pragma unroll 2
    for (int i = 0; i < D_ / 2; ++i) {
        const int d = dbeg + i;
        const d2_t w = W_T[(size_t)d * KPAD + klane];
        #pragma unroll
        for (int bl = 0; bl < BT; ++bl) {
            const double x = (double)xq[(size_t)(b0 + bl) * D_ + d]; // uniform bcast
            dot[bl] += x * w.x;
            sq[bl]  += (x * x) * w.y;
        }
    }

    if (dhalf == 1) {
        #pragma unroll
        for (int bl = 0; bl < BT; ++bl) {
            s_hd[bl][klane] = dot[bl];
            s_hq[bl][klane] = sq[bl];
        }
    }
    __syncthreads();
    if (dhalf == 0) {
        #pragma unroll
        for (int bl = 0; bl < BT; ++bl)
            s_aq[bl][klane] = (dot[bl] + s_hd[bl][klane]) /
                              fmax(sqrt(sq[bl] + s_hq[bl][klane]), 1e-12);
    }
    __syncthreads();

    const int wave = t >> 6, lane = t & 63;
    // wave w handles b-rows w and w+4; tie -> lowest index (lax.top_k stable)
    #pragma unroll
    for (int half = 0; half < 2; ++half) {
        const int bl = wave + half * 4;
        double v0 = s_aq[bl][lane];                                  // lane<64<100
        double v1 = (lane + 64 < POOL_) ? s_aq[bl][lane + 64] : -1e300;
        #pragma unroll
        for (int r = 0; r < TOPK_; ++r) {
            double v; int ki;
            if (v0 >= v1) { v = v0; ki = lane; }
            else          { v = v1; ki = lane + 64; }
            #pragma unroll
            for (int off = 32; off >= 1; off >>= 1) {
                double ov = __shfl_xor(v, off);
                int    oi = __shfl_xor(ki, off);
                if (ov > v || (ov == v && oi < ki)) { v = ov; ki = oi; }
            }
            if (lane == 0) s_idx[bl][r] = ki;
            if (ki == lane)      v0 = -1e300;
            if (ki == lane + 64) v1 = -1e300;
        }
    }
    __syncthreads();

    // gather: BT rows x 8 prompt-rows x 192 float4 = 12288 units / 256 threads
    for (int w = t; w < BT * PLEN_ * 192; w += 256) {
        const int bl  = w / (PLEN_ * 192);
        const int rem = w % (PLEN_ * 192);
        const int j = rem / 192, c = rem % 192;
        const int i0 = s_idx[bl][0], i1 = s_idx[bl][1], i2 = s_idx[bl][2];
        const int b = b0 + bl;
        const f4_t* __restrict__ q0 = (const f4_t*)(p + (size_t)(j * POOL_ + i0) * D_);
        const f4_t* __restrict__ q1 = (const f4_t*)(p + (size_t)(j * POOL_ + i1) * D_);
        const f4_t* __restrict__ q2 = (const f4_t*)(p + (size_t)(j * POOL_ + i2) * D_);
        f4_t v = q0[c] + q1[c] + q2[c];
        float* dst = (j < 4) ? out + ((size_t)b * 4 + j) * D_
                             : out + EK_ELEMS + ((size_t)b * 4 + (j - 4)) * D_;
        ((f4_t*)dst)[c] = v;
    }
}

extern "C" void kernel_launch(void* const* d_in, const int* in_sizes, int n_in,
                              void* d_out, int out_size, void* d_ws, size_t ws_size,
                              hipStream_t stream) {
    const float* x_querry = (const float*)d_in[0];   // (1024, 768)
    const float* x_block  = (const float*)d_in[1];   // (1024, 197, 768)
    const float* K        = (const float*)d_in[2];   // (100, 768)
    const float* A        = (const float*)d_in[3];   // (100, 768)
    const float* p        = (const float*)d_in[4];   // (8, 100, 768)
    // d_in[5] = l (unused)

    float* out = (float*)d_out;

    // workspace: W_T interleaved {u,v} double2 [768][128]
    d2_t* W_T = (d2_t*)d_ws;                         // 1,572,864 B

    prep_kernel<<<KPAD, 256, 0, stream>>>(A, K, W_T);
    fused_kernel<<<NBLOCKS, 256, 0, stream>>>(x_querry, W_T, p,
                                              (const f4_t*)x_block, out);
}

// Round 12
// 265.943 us; speedup vs baseline: 1.1652x; 1.1652x over previous
//
#include <hip/hip_runtime.h>
#include <hip/hip_bf16.h>

// Problem shapes (fixed by setup_inputs)
#define B_    1024
#define D_    768
#define POOL_ 100
#define KPAD  128                        // pool padded for transposed layout
#define PLEN_ 8
#define TOPK_ 3
#define EK_ELEMS (B_ * 4 * D_)           // 3,145,728
#define XB_ELEMS (B_ * 197 * D_)         // 154,976,256
#define XB_F4    (XB_ELEMS / 4)          // 38,744,064 float4s

#define BT 4                             // b-rows per score block (R11 lesson: 8 hurt)
#define SCORE_BLOCKS (B_ / BT)           // 256
#define THREADS 512
#define COPY_BLOCKS  4096                // 4096x512 == same pattern as 8192x256 (R7-proven)
#define NBLOCKS (SCORE_BLOCKS + COPY_BLOCKS)

typedef float  f4_t __attribute__((ext_vector_type(4)));
typedef double d2_t __attribute__((ext_vector_type(2)));

// ---------------------------------------------------------------------------
// Kernel 1: prep. For k<100: sm = softmax(A[k,:]), n = ||K[k,:]||, write
//   W_T[d][k] = { sm_d * K[k,d]/n,  sm_d * sm_d }   (double2, k-contiguous)
// For k in [100,128): zero pad columns.
// ---------------------------------------------------------------------------
__global__ void prep_kernel(const float* __restrict__ A, const float* __restrict__ K,
                            d2_t* __restrict__ W_T) {
    const int k = blockIdx.x;
    const int t = threadIdx.x;

    if (k >= POOL_) {
        for (int d = t; d < D_; d += 256)
            W_T[(size_t)d * KPAD + k] = d2_t{0.0, 0.0};
        return;
    }

    const int wave = t >> 6, lane = t & 63;
    __shared__ double red[4];

    double m = -1e300;
    for (int d = t; d < D_; d += 256) m = fmax(m, (double)A[k * D_ + d]);
    #pragma unroll
    for (int off = 32; off >= 1; off >>= 1) m = fmax(m, __shfl_xor(m, off));
    if (lane == 0) red[wave] = m;
    __syncthreads();
    m = fmax(fmax(red[0], red[1]), fmax(red[2], red[3]));
    __syncthreads();

    double s = 0.0;
    for (int d = t; d < D_; d += 256) s += exp((double)A[k * D_ + d] - m);
    #pragma unroll
    for (int off = 32; off >= 1; off >>= 1) s += __shfl_xor(s, off);
    if (lane == 0) red[wave] = s;
    __syncthreads();
    s = red[0] + red[1] + red[2] + red[3];
    __syncthreads();

    double ss = 0.0;
    for (int d = t; d < D_; d += 256) {
        double v = (double)K[k * D_ + d];
        ss += v * v;
    }
    #pragma unroll
    for (int off = 32; off >= 1; off >>= 1) ss += __shfl_xor(ss, off);
    if (lane == 0) red[wave] = ss;
    __syncthreads();
    ss = red[0] + red[1] + red[2] + red[3];
    const double n = fmax(sqrt(ss), 1e-12);

    for (int d = t; d < D_; d += 256) {
        const double smd = exp((double)A[k * D_ + d] - m) / s;
        W_T[(size_t)d * KPAD + k] = d2_t{smd * ((double)K[k * D_ + d] / n),
                                         smd * smd};
    }
}

// ---------------------------------------------------------------------------
// Kernel 2 (fused score + copy):
//  blocks [0,256):  score BT=4 rows, 512 thr = 128 klane x 4 d-quarter.
//    R11 lesson: score duration = latency x serial-work / waves-per-block;
//    traffic-reduction (BT=8) HURT. So: halve serial chain (192 iters),
//    double waves (8/block), stage xq in LDS f64 (broadcast ds_read, no
//    in-loop cvt), keep exactly one global d2 load per iter, unroll x8.
//  blocks [256, 4352): plain grid-stride float4 copy, 512 thr x 4096 blocks
//    == identical address pattern to the R7-proven 8192x256 (6.4 TB/s).
// ---------------------------------------------------------------------------
__global__ void __launch_bounds__(THREADS)
fused_kernel(const float* __restrict__ xq,
             const d2_t* __restrict__ W_T,
             const float* __restrict__ p,
             const f4_t* __restrict__ xb,
             float* __restrict__ out) {
    const int t = threadIdx.x;

    if (blockIdx.x >= SCORE_BLOCKS) {
        // ---------------- copy role ----------------
        f4_t* __restrict__ dst = (f4_t*)(out + 2 * (size_t)EK_ELEMS);
        size_t i = (size_t)(blockIdx.x - SCORE_BLOCKS) * THREADS + t;
        const size_t stride = (size_t)COPY_BLOCKS * THREADS;
        for (; i < (size_t)XB_F4; i += stride)
            dst[i] = xb[i];
        return;
    }

    // ---------------- score role ----------------
    __shared__ double s_xq[BT][D_];          // 24 KB, f64 (cvt once at stage)
    __shared__ double s_pd[3][BT][KPAD];     // 12 KB, dq=1..3 partial dots
    __shared__ double s_pq[3][BT][KPAD];     // 12 KB, dq=1..3 partial sqs
    __shared__ double s_aq[BT][KPAD];        // 4 KB
    __shared__ int    s_idx[BT][TOPK_];

    const int b0    = blockIdx.x * BT;
    const int klane = t & (KPAD - 1);
    const int dq    = t >> 7;                // 0..3, wave-uniform

    for (int i = t; i < BT * D_; i += THREADS)
        s_xq[i / D_][i % D_] = (double)xq[(size_t)(b0 + i / D_) * D_ + (i % D_)];
    __syncthreads();

    double dot[BT], sq[BT];
    #pragma unroll
    for (int bl = 0; bl < BT; ++bl) { dot[bl] = 0.0; sq[bl] = 0.0; }

    const int dbeg = dq * (D_ / 4);
    #pragma unroll 8
    for (int i = 0; i < D_ / 4; ++i) {
        const int d = dbeg + i;
        const d2_t w = W_T[(size_t)d * KPAD + klane];
        #pragma unroll
        for (int bl = 0; bl < BT; ++bl) {
            const double x = s_xq[bl][d];    // wave-broadcast ds_read_b64
            dot[bl] += x * w.x;
            sq[bl]  += (x * x) * w.y;
        }
    }

    if (dq > 0) {
        #pragma unroll
        for (int bl = 0; bl < BT; ++bl) {
            s_pd[dq - 1][bl][klane] = dot[bl];
            s_pq[dq - 1][bl][klane] = sq[bl];
        }
    }
    __syncthreads();
    if (dq == 0) {
        #pragma unroll
        for (int bl = 0; bl < BT; ++bl) {
            const double dd = dot[bl] + s_pd[0][bl][klane] + s_pd[1][bl][klane] + s_pd[2][bl][klane];
            const double qq = sq[bl]  + s_pq[0][bl][klane] + s_pq[1][bl][klane] + s_pq[2][bl][klane];
            s_aq[bl][klane] = dd / fmax(sqrt(qq), 1e-12);
        }
    }
    __syncthreads();

    const int wave = t >> 6, lane = t & 63;
    if (wave < BT) {
        // wave w: top-3 for b-row w; lane covers k=lane and k=lane+64;
        // tie -> lowest index (matches lax.top_k stability)
        double v0 = s_aq[wave][lane];                                // lane<64<100
        double v1 = (lane + 64 < POOL_) ? s_aq[wave][lane + 64] : -1e300;
        #pragma unroll
        for (int r = 0; r < TOPK_; ++r) {
            double v; int ki;
            if (v0 >= v1) { v = v0; ki = lane; }
            else          { v = v1; ki = lane + 64; }
            #pragma unroll
            for (int off = 32; off >= 1; off >>= 1) {
                double ov = __shfl_xor(v, off);
                int    oi = __shfl_xor(ki, off);
                if (ov > v || (ov == v && oi < ki)) { v = ov; ki = oi; }
            }
            if (lane == 0) s_idx[wave][r] = ki;
            if (ki == lane)      v0 = -1e300;
            if (ki == lane + 64) v1 = -1e300;
        }
    }
    __syncthreads();

    // gather: BT rows x 8 prompt-rows x 192 float4 = 6144 units / 512 threads
    for (int w = t; w < BT * PLEN_ * 192; w += THREADS) {
        const int bl  = w / (PLEN_ * 192);
        const int rem = w % (PLEN_ * 192);
        const int j = rem / 192, c = rem % 192;
        const int i0 = s_idx[bl][0], i1 = s_idx[bl][1], i2 = s_idx[bl][2];
        const int b = b0 + bl;
        const f4_t* __restrict__ q0 = (const f4_t*)(p + (size_t)(j * POOL_ + i0) * D_);
        const f4_t* __restrict__ q1 = (const f4_t*)(p + (size_t)(j * POOL_ + i1) * D_);
        const f4_t* __restrict__ q2 = (const f4_t*)(p + (size_t)(j * POOL_ + i2) * D_);
        f4_t v = q0[c] + q1[c] + q2[c];
        float* dst = (j < 4) ? out + ((size_t)b * 4 + j) * D_
                             : out + EK_ELEMS + ((size_t)b * 4 + (j - 4)) * D_;
        ((f4_t*)dst)[c] = v;
    }
}

extern "C" void kernel_launch(void* const* d_in, const int* in_sizes, int n_in,
                              void* d_out, int out_size, void* d_ws, size_t ws_size,
                              hipStream_t stream) {
    const float* x_querry = (const float*)d_in[0];   // (1024, 768)
    const float* x_block  = (const float*)d_in[1];   // (1024, 197, 768)
    const float* K        = (const float*)d_in[2];   // (100, 768)
    const float* A        = (const float*)d_in[3];   // (100, 768)
    const float* p        = (const float*)d_in[4];   // (8, 100, 768)
    // d_in[5] = l (unused)

    float* out = (float*)d_out;

    // workspace: W_T interleaved {u,v} double2 [768][128]
    d2_t* W_T = (d2_t*)d_ws;                         // 1,572,864 B

    prep_kernel<<<KPAD, 256, 0, stream>>>(A, K, W_T);
    fused_kernel<<<NBLOCKS, THREADS, 0, stream>>>(x_querry, W_T, p,
                                                  (const f4_t*)x_block, out);
}

// Round 13
// 247.139 us; speedup vs baseline: 1.2538x; 1.0761x over previous
//
#include <hip/hip_runtime.h>
#include <hip/hip_bf16.h>

// Problem shapes (fixed by setup_inputs)
#define B_    1024
#define D_    768
#define POOL_ 100
#define KPAD  128                        // pool padded for transposed layout
#define PLEN_ 8
#define TOPK_ 3
#define EK_ELEMS (B_ * 4 * D_)           // 3,145,728
#define XB_ELEMS (B_ * 197 * D_)         // 154,976,256
#define XB_F4    (XB_ELEMS / 4)          // 38,744,064 float4s

#define BT 8                             // b-rows per score block
#define SCORE_BLOCKS (B_ / BT)           // 128
#define THREADS 512
#define COPY_BLOCKS  4096                // same pattern as R7-proven 8192x256
#define NBLOCKS (SCORE_BLOCKS + COPY_BLOCKS)

typedef float  f4_t __attribute__((ext_vector_type(4)));
typedef double d2_t __attribute__((ext_vector_type(2)));

// ---------------------------------------------------------------------------
// Kernel 1: prep. For k<100: sm = softmax(A[k,:]), n = ||K[k,:]||, write
//   W_T[d][k] = { sm_d * K[k,d]/n,  sm_d * sm_d }   (double2, k-contiguous)
// For k in [100,128): zero pad columns.
// ---------------------------------------------------------------------------
__global__ void prep_kernel(const float* __restrict__ A, const float* __restrict__ K,
                            d2_t* __restrict__ W_T) {
    const int k = blockIdx.x;
    const int t = threadIdx.x;

    if (k >= POOL_) {
        for (int d = t; d < D_; d += 256)
            W_T[(size_t)d * KPAD + k] = d2_t{0.0, 0.0};
        return;
    }

    const int wave = t >> 6, lane = t & 63;
    __shared__ double red[4];

    double m = -1e300;
    for (int d = t; d < D_; d += 256) m = fmax(m, (double)A[k * D_ + d]);
    #pragma unroll
    for (int off = 32; off >= 1; off >>= 1) m = fmax(m, __shfl_xor(m, off));
    if (lane == 0) red[wave] = m;
    __syncthreads();
    m = fmax(fmax(red[0], red[1]), fmax(red[2], red[3]));
    __syncthreads();

    double s = 0.0;
    for (int d = t; d < D_; d += 256) s += exp((double)A[k * D_ + d] - m);
    #pragma unroll
    for (int off = 32; off >= 1; off >>= 1) s += __shfl_xor(s, off);
    if (lane == 0) red[wave] = s;
    __syncthreads();
    s = red[0] + red[1] + red[2] + red[3];
    __syncthreads();

    double ss = 0.0;
    for (int d = t; d < D_; d += 256) {
        double v = (double)K[k * D_ + d];
        ss += v * v;
    }
    #pragma unroll
    for (int off = 32; off >= 1; off >>= 1) ss += __shfl_xor(ss, off);
    if (lane == 0) red[wave] = ss;
    __syncthreads();
    ss = red[0] + red[1] + red[2] + red[3];
    const double n = fmax(sqrt(ss), 1e-12);

    for (int d = t; d < D_; d += 256) {
        const double smd = exp((double)A[k * D_ + d] - m) / s;
        W_T[(size_t)d * KPAD + k] = d2_t{smd * ((double)K[k * D_ + d] / n),
                                         smd * smd};
    }
}

// ---------------------------------------------------------------------------
// Kernel 2 (fused score + copy):
//  blocks [0,128):  score BT=8 rows, 512 thr = 128 klane x 4 d-quarter.
//    R12 model: fused time = (copy 1.24 GB + W re-fetch #blocks x 1.5 MB) /
//    HBM BW + score tail. BT 4->8 halves W traffic (384->192 MB) while the
//    R12 structure keeps the serial chain at 192 iters and 8 waves/block
//    (R11's BT=8 failure was the 384-iter serial chain at 256 thr).
//    LDS fit: xq staged f32 (24 KB, cvt in-loop), ONE d2 partial buffer
//    (16 KB) reused over 3 reduction rounds, aq f64 (8 KB) -> 48.2 KB.
//  blocks [128, 4224): plain grid-stride float4 copy (R7-proven pattern).
// ---------------------------------------------------------------------------
__global__ void __launch_bounds__(THREADS)
fused_kernel(const float* __restrict__ xq,
             const d2_t* __restrict__ W_T,
             const float* __restrict__ p,
             const f4_t* __restrict__ xb,
             float* __restrict__ out) {
    const int t = threadIdx.x;

    if (blockIdx.x >= SCORE_BLOCKS) {
        // ---------------- copy role ----------------
        f4_t* __restrict__ dst = (f4_t*)(out + 2 * (size_t)EK_ELEMS);
        size_t i = (size_t)(blockIdx.x - SCORE_BLOCKS) * THREADS + t;
        const size_t stride = (size_t)COPY_BLOCKS * THREADS;
        for (; i < (size_t)XB_F4; i += stride)
            dst[i] = xb[i];
        return;
    }

    // ---------------- score role ----------------
    __shared__ float  s_xqf[BT][D_];         // 24 KB, f32 stage
    __shared__ d2_t   s_buf[BT][KPAD];       // 16 KB, reduction buffer (reused)
    __shared__ double s_aq[BT][KPAD];        // 8 KB
    __shared__ int    s_idx[BT][TOPK_];

    const int b0    = blockIdx.x * BT;
    const int klane = t & (KPAD - 1);
    const int dq    = t >> 7;                // 0..3, wave-uniform

    for (int i = t; i < BT * D_; i += THREADS)
        s_xqf[i / D_][i % D_] = xq[(size_t)(b0 + i / D_) * D_ + (i % D_)];
    __syncthreads();

    double dot[BT], sq[BT];
    #pragma unroll
    for (int bl = 0; bl < BT; ++bl) { dot[bl] = 0.0; sq[bl] = 0.0; }

    const int dbeg = dq * (D_ / 4);
    #pragma unroll 4
    for (int i = 0; i < D_ / 4; ++i) {
        const int d = dbeg + i;
        const d2_t w = W_T[(size_t)d * KPAD + klane];
        #pragma unroll
        for (int bl = 0; bl < BT; ++bl) {
            const double x = (double)s_xqf[bl][d];   // bcast ds_read + cvt
            dot[bl] += x * w.x;
            sq[bl]  += (x * x) * w.y;
        }
    }

    // 3 reduction rounds through one buffer: dq==r writes, dq==0 accumulates
    #pragma unroll
    for (int r = 1; r < 4; ++r) {
        if (dq == r) {
            #pragma unroll
            for (int bl = 0; bl < BT; ++bl)
                s_buf[bl][klane] = d2_t{dot[bl], sq[bl]};
        }
        __syncthreads();
        if (dq == 0) {
            #pragma unroll
            for (int bl = 0; bl < BT; ++bl) {
                dot[bl] += s_buf[bl][klane].x;
                sq[bl]  += s_buf[bl][klane].y;
            }
        }
        __syncthreads();
    }
    if (dq == 0) {
        #pragma unroll
        for (int bl = 0; bl < BT; ++bl)
            s_aq[bl][klane] = dot[bl] / fmax(sqrt(sq[bl]), 1e-12);
    }
    __syncthreads();

    const int wave = t >> 6, lane = t & 63;
    if (wave < 4) {
        // wave w: top-3 for rows w and w+4; tie -> lowest index (lax.top_k)
        #pragma unroll
        for (int half = 0; half < 2; ++half) {
            const int bl = wave + half * 4;
            double v0 = s_aq[bl][lane];                              // lane<64<100
            double v1 = (lane + 64 < POOL_) ? s_aq[bl][lane + 64] : -1e300;
            #pragma unroll
            for (int r = 0; r < TOPK_; ++r) {
                double v; int ki;
                if (v0 >= v1) { v = v0; ki = lane; }
                else          { v = v1; ki = lane + 64; }
                #pragma unroll
                for (int off = 32; off >= 1; off >>= 1) {
                    double ov = __shfl_xor(v, off);
                    int    oi = __shfl_xor(ki, off);
                    if (ov > v || (ov == v && oi < ki)) { v = ov; ki = oi; }
                }
                if (lane == 0) s_idx[bl][r] = ki;
                if (ki == lane)      v0 = -1e300;
                if (ki == lane + 64) v1 = -1e300;
            }
        }
    }
    __syncthreads();

    // gather: BT rows x 8 prompt-rows x 192 float4 = 12288 units / 512 threads
    for (int w = t; w < BT * PLEN_ * 192; w += THREADS) {
        const int bl  = w / (PLEN_ * 192);
        const int rem = w % (PLEN_ * 192);
        const int j = rem / 192, c = rem % 192;
        const int i0 = s_idx[bl][0], i1 = s_idx[bl][1], i2 = s_idx[bl][2];
        const int b = b0 + bl;
        const f4_t* __restrict__ q0 = (const f4_t*)(p + (size_t)(j * POOL_ + i0) * D_);
        const f4_t* __restrict__ q1 = (const f4_t*)(p + (size_t)(j * POOL_ + i1) * D_);
        const f4_t* __restrict__ q2 = (const f4_t*)(p + (size_t)(j * POOL_ + i2) * D_);
        f4_t v = q0[c] + q1[c] + q2[c];
        float* dst = (j < 4) ? out + ((size_t)b * 4 + j) * D_
                             : out + EK_ELEMS + ((size_t)b * 4 + (j - 4)) * D_;
        ((f4_t*)dst)[c] = v;
    }
}

extern "C" void kernel_launch(void* const* d_in, const int* in_sizes, int n_in,
                              void* d_out, int out_size, void* d_ws, size_t ws_size,
                              hipStream_t stream) {
    const float* x_querry = (const float*)d_in[0];   // (1024, 768)
    const float* x_block  = (const float*)d_in[1];   // (1024, 197, 768)
    const float* K        = (const float*)d_in[2];   // (100, 768)
    const float* A        = (const float*)d_in[3];   // (100, 768)
    const float* p        = (const float*)d_in[4];   // (8, 100, 768)
    // d_in[5] = l (unused)

    float* out = (float*)d_out;

    // workspace: W_T interleaved {u,v} double2 [768][128]
    d2_t* W_T = (d2_t*)d_ws;                         // 1,572,864 B

    prep_kernel<<<KPAD, 256, 0, stream>>>(A, K, W_T);
    fused_kernel<<<NBLOCKS, THREADS, 0, stream>>>(x_querry, W_T, p,
                                                  (const f4_t*)x_block, out);
}